// Round 1
// baseline (499.647 us; speedup 1.0000x reference)
//
#include <hip/hip_runtime.h>
#include <stdint.h>

#define NPIX   131072      // 32*64*64 per batch
#define HALFN  65536
#define NBIN   4096
#define CAP    4096
#define KSEL   50
#define SENT_HARD 0xFFFFFFFFu
#define SENT_NONE 0xFFFFFFFEu

__host__ __device__ __forceinline__ uint32_t rotl32(uint32_t v, int d) {
  return (v << d) | (v >> (32 - d));
}

// JAX Threefry-2x32 block (20 rounds), matches jax/_src/prng.py exactly.
__host__ __device__ __forceinline__ void tf_block(uint32_t k0, uint32_t k1,
                                                  uint32_t c0, uint32_t c1,
                                                  uint32_t& o0, uint32_t& o1) {
  uint32_t ks2 = k0 ^ k1 ^ 0x1BD11BDAu;
  uint32_t x0 = c0 + k0, x1 = c1 + k1;
#define TF_R(r) { x0 += x1; x1 = rotl32(x1, (r)); x1 ^= x0; }
  TF_R(13) TF_R(15) TF_R(26) TF_R(6)   x0 += k1;  x1 += ks2 + 1u;
  TF_R(17) TF_R(29) TF_R(16) TF_R(24)  x0 += ks2; x1 += k0  + 2u;
  TF_R(13) TF_R(15) TF_R(26) TF_R(6)   x0 += k0;  x1 += k1  + 3u;
  TF_R(17) TF_R(29) TF_R(16) TF_R(24)  x0 += k1;  x1 += ks2 + 4u;
  TF_R(13) TF_R(15) TF_R(26) TF_R(6)   x0 += ks2; x1 += k0  + 5u;
#undef TF_R
  o0 = x0; o1 = x1;
}

__global__ void k_zero(int* hist, float* out) {
  int i = blockIdx.x * blockDim.x + threadIdx.x;
  if (i < 2 * NBIN) hist[i] = 0;
  if (i == 0) out[0] = 0.f;
}

// Pass 1: per pixel, classify + compute Threefry uniform score, histogram easy scores.
__global__ void k_scores(const int* __restrict__ labels, const int* __restrict__ predict,
                         uint32_t* __restrict__ scores, int* __restrict__ hist,
                         uint32_t k00, uint32_t k01, uint32_t k10, uint32_t k11) {
  int gid = blockIdx.x * blockDim.x + threadIdx.x;
  if (gid >= 2 * NPIX) return;
  int b = gid >> 17;
  int n = gid & (NPIX - 1);
  int yh = labels[gid], yp = predict[gid];
  uint32_t sval;
  if (yh == 1 && yp == 1) {                 // easy positive
    uint32_t ka = b ? k10 : k00, kb = b ? k11 : k01;
    uint32_t o0, o1, bits;
    if (n < HALFN) { tf_block(ka, kb, (uint32_t)n, (uint32_t)(n + HALFN), o0, o1); bits = o0; }
    else           { tf_block(ka, kb, (uint32_t)(n - HALFN), (uint32_t)n, o0, o1); bits = o1; }
    float u = __uint_as_float((bits >> 9) | 0x3F800000u) - 1.0f;   // jax uniform [0,1)
    sval = __float_as_uint(u);              // <= 0x3F7FFFFF
    int bin = (int)(u * (float)NBIN); if (bin > NBIN - 1) bin = NBIN - 1; if (bin < 0) bin = 0;
    atomicAdd(&hist[b * NBIN + bin], 1);
  } else if (yh == 0 && yp == 0) {          // hard
    sval = SENT_HARD;
  } else {
    sval = SENT_NONE;
  }
  scores[gid] = sval;
}

// Pass 2: one block per batch. Ordered first-50 hard extraction + exact top-50 easy selection.
__global__ __launch_bounds__(1024) void k_select(const uint32_t* __restrict__ scores,
                                                 const int* __restrict__ hist,
                                                 int* __restrict__ easy_out,
                                                 int* __restrict__ hard_out) {
  int b = blockIdx.x;
  int tid = threadIdx.x;
  int wv = tid >> 6, lane = tid & 63;
  __shared__ int sh_hist[NBIN];
  __shared__ uint64_t cand[CAP];
  __shared__ int wavecnt[16];
  __shared__ uint64_t wred[16];
  __shared__ int hardbuf[KSEL];
  __shared__ int s_t, s_cc, s_base;
  __shared__ uint64_t s_win;

  for (int i = tid; i < NBIN; i += 1024) sh_hist[i] = hist[b * NBIN + i];
  if (tid == 0) { s_cc = 0; s_base = 0; }
  __syncthreads();
  if (tid == 0) {
    int acc = 0, t = 0; bool found = false;
    for (int bin = NBIN - 1; bin >= 0; --bin) {
      acc += sh_hist[bin];
      if (!found && acc >= KSEL) { t = bin; found = true; }
    }
    s_t = found ? t : 0;
  }
  __syncthreads();
  int t = s_t;

  // Chunked ordered scan: n = c*1024 + tid
  for (int c = 0; c < NPIX / 1024; ++c) {
    int n = c * 1024 + tid;
    uint32_t val = scores[b * NPIX + n];
    bool ph = (val == SENT_HARD);
    uint64_t bal = __ballot(ph);
    if (lane == 0) wavecnt[wv] = __popcll(bal);
    __syncthreads();
    int pre = 0;
    for (int w = 0; w < wv; ++w) pre += wavecnt[w];
    int tot = pre;
    for (int w = wv; w < 16; ++w) tot += wavecnt[w];
    if (ph) {
      int rank = s_base + pre + __popcll(bal & ((1ull << lane) - 1ull));
      if (rank < KSEL) hardbuf[rank] = n;
    }
    if (val < SENT_NONE) {  // easy
      float u = __uint_as_float(val);
      int bin = (int)(u * (float)NBIN); if (bin > NBIN - 1) bin = NBIN - 1;
      if (bin >= t) {
        int pos = atomicAdd(&s_cc, 1);
        if (pos < CAP) cand[pos] = ((uint64_t)val << 32) | (uint32_t)(~(uint32_t)n);
      }
    }
    __syncthreads();
    if (tid == 0) s_base += tot;
    __syncthreads();
  }

  int cc = s_cc; if (cc > CAP) cc = CAP;

  // Top-50 by packed key: descending score, ascending index tie-break (keys unique).
  for (int k = 0; k < KSEL; ++k) {
    uint64_t lmax = 0;
    for (int i = tid; i < cc; i += 1024) { uint64_t v = cand[i]; if (v > lmax) lmax = v; }
    for (int off = 32; off; off >>= 1) {
      uint64_t o = __shfl_down(lmax, off);
      if (o > lmax) lmax = o;
    }
    if (lane == 0) wred[wv] = lmax;
    __syncthreads();
    if (tid == 0) {
      uint64_t m = 0;
      for (int w = 0; w < 16; ++w) if (wred[w] > m) m = wred[w];
      s_win = m;
    }
    __syncthreads();
    uint64_t win = s_win;
    if (win != 0) {
      for (int i = tid; i < cc; i += 1024) if (cand[i] == win) cand[i] = 0;
      if (tid == 0) easy_out[b * 64 + k] = (int)(~(uint32_t)win);
      __syncthreads();
    } else {
      // fewer than 50 easy: fill with ascending non-easy indices (top_k over -1 ties)
      if (tid == 0) {
        int slot = k;
        for (int n = 0; n < NPIX && slot < KSEL; ++n)
          if (scores[b * NPIX + n] >= SENT_NONE) easy_out[b * 64 + slot++] = n;
      }
      __syncthreads();
      break;
    }
  }

  // hard fallback if fewer than 50 hard (stable argsort tail = ascending non-hard)
  if (tid == 0) {
    int h = s_base; if (h > KSEL) h = KSEL;
    int slot = h;
    for (int n = 0; n < NPIX && slot < KSEL; ++n)
      if (scores[b * NPIX + n] != SENT_HARD) hardbuf[slot++] = n;
  }
  __syncthreads();
  if (tid < KSEL) hard_out[b * 64 + tid] = hardbuf[tid];
}

// Pass 3: gather 200 rows of D=128 from feats (layout [B,D,N]) and L2-normalize.
__global__ void k_gather(const float* __restrict__ feats, const int* __restrict__ easy_out,
                         const int* __restrict__ hard_out, float* __restrict__ A) {
  int r = blockIdx.x;          // A[2i+v] = X_[v][i]
  int d = threadIdx.x;         // 0..127
  int v = r & 1, i = r >> 1;
  int n = (i < KSEL) ? easy_out[v * 64 + i] : hard_out[v * 64 + (i - KSEL)];
  float val = feats[((size_t)(v * 128 + d)) * NPIX + (size_t)n];
  float sq = val * val;
  for (int off = 32; off; off >>= 1) sq += __shfl_down(sq, off);
  __shared__ float wsum[2];
  __shared__ float s_inv;
  if ((d & 63) == 0) wsum[d >> 6] = sq;
  __syncthreads();
  if (d == 0) s_inv = 1.0f / fmaxf(sqrtf(wsum[0] + wsum[1]), 1e-12f);
  __syncthreads();
  A[r * 128 + d] = val * s_inv;
}

// Pass 4: per-row contrastive terms.
__global__ __launch_bounds__(256) void k_loss(const float* __restrict__ A,
                                              float* __restrict__ rowres) {
  int r = blockIdx.x;   // 0..199
  int c = threadIdx.x;  // 0..255
  __shared__ float arow[128];
  __shared__ float red[256];
  if (c < 128) arow[c] = A[r * 128 + c];
  __syncthreads();
  bool valid = c < 200;
  float logit = -1e30f;
  if (valid) {
    const float* Ac = A + c * 128;
    float dot = 0.f;
#pragma unroll 8
    for (int d = 0; d < 128; ++d) dot += arow[d] * Ac[d];
    logit = dot * 10.0f;      // / BASE_TEMP (0.1)
  }
  red[c] = logit;
  __syncthreads();
  for (int s = 128; s; s >>= 1) { if (c < s) { float o = red[c + s]; if (o > red[c]) red[c] = o; } __syncthreads(); }
  float M = red[0];
  __syncthreads();
  float e = valid ? expf(logit - M) : 0.f;
  bool sameblk = valid && ((r / 100) == (c / 100));
  red[c] = (valid && !sameblk) ? e : 0.f;   // neg_mask = 1 - mask0
  __syncthreads();
  for (int s = 128; s; s >>= 1) { if (c < s) red[c] += red[c + s]; __syncthreads(); }
  float neg = red[0];
  __syncthreads();
  bool msk = sameblk && !(r < 100 && c == r);   // mask0 * logits_mask
  red[c] = msk ? ((logit - M) - logf(e + neg)) : 0.f;
  __syncthreads();
  for (int s = 128; s; s >>= 1) { if (c < s) red[c] += red[c + s]; __syncthreads(); }
  if (c == 0) {
    float denom = (r < 100) ? 99.f : 100.f;
    rowres[r] = red[0] / denom;
  }
}

__global__ void k_final(const float* __restrict__ rowres, float* __restrict__ out) {
  int tid = threadIdx.x;
  __shared__ float red[256];
  red[tid] = (tid < 200) ? rowres[tid] : 0.f;
  __syncthreads();
  for (int s = 128; s; s >>= 1) { if (tid < s) red[tid] += red[tid + s]; __syncthreads(); }
  if (tid == 0) out[0] = -(red[0] / 20.0f) / 200.0f;   // -(mean_lpp/TEMP).mean()
}

extern "C" void kernel_launch(void* const* d_in, const int* in_sizes, int n_in,
                              void* d_out, int out_size, void* d_ws, size_t ws_size,
                              hipStream_t stream) {
  const float* feats  = (const float*)d_in[0];
  const int* labels   = (const int*)d_in[1];
  const int* predict  = (const int*)d_in[2];
  float* out = (float*)d_out;

  char* ws = (char*)d_ws;
  uint32_t* scores = (uint32_t*)ws;                         // 2*NPIX u32 = 1 MiB
  int* hist  = (int*)(ws + (size_t)2 * NPIX * 4);           // 2*4096 int
  int* easy  = (int*)((char*)hist + 2 * NBIN * 4);          // 2*64 int
  int* hard  = easy + 2 * 64;                               // 2*64 int
  float* A   = (float*)(hard + 2 * 64);                     // 200*128 f32
  float* rowres = A + 200 * 128;                            // 200 f32

  // Batch keys: key(42) = (0,42); split -> blocks (0,2) and (1,3) (host-side, deterministic).
  uint32_t a0, a1, b0, b1;
  tf_block(0u, 42u, 0u, 2u, a0, a1);
  tf_block(0u, 42u, 1u, 3u, b0, b1);
  // keys[0] = (a0, b0), keys[1] = (a1, b1)

  k_zero<<<(2 * NBIN + 255) / 256, 256, 0, stream>>>(hist, out);
  k_scores<<<(2 * NPIX) / 256, 256, 0, stream>>>(labels, predict, scores, hist, a0, b0, a1, b1);
  k_select<<<2, 1024, 0, stream>>>(scores, hist, easy, hard);
  k_gather<<<200, 128, 0, stream>>>(feats, easy, hard, A);
  k_loss<<<200, 256, 0, stream>>>(A, rowres);
  k_final<<<1, 256, 0, stream>>>(rowres, out);
}